// Round 15
// baseline (33.251 us; speedup 1.0000x reference)
//
#include <hip/hip_runtime.h>
#include <math.h>

// Problem constants (from setup_inputs)
#define BB 8
#define HW 4096
#define LTXT 8192
#define GG 4096
#define DD 256

// Worker grid: 1120 blocks x 128 threads.
// Chain blocks (1024): block = 128 rows. Lane j of each wave owns row PAIR
// (rowBase+j, rowBase+j+64) packed in v2f lanes (R14's zero-swizzle packing).
// Wave h (= t>>6, wave-uniform) processes quat half [32h, 32h+32) -> weight
// addresses stay wave-uniform, serial spine halves, waves double vs R14
// (2048 chain waves = 2/SIMD). Halves joined via 2KB LDS exchange; packed
// butterfly over lanes; block product = (rows 0-63).x * (rows 64-127).y.
//   [0,256)     vision: b = id/32,  chunk = id%32
//   [256,768)   text:   b = (id-256)/64, chunk = %64
//   [768,1024)  genomic: b = (id-768)/32, chunk = %32
//   [1024,1056) vision audit (32 blocks, thread = row)
//   [1056,1120) text audit (64 blocks, thread = position)
//
// Normalization (validated family, R13/R14 absmax 0): multiply RAW quats;
// per batch exact 2^-e2 rescale (exponent extract), accumulate mantissa
// product M and rr = sum rsq(n2); once per 32-quat segment: divide by
// sqrt(M) * (1 + 1e-8f*rr)  [= prod(n_i + 1e-8f) to 2nd order].
//
// ws: floats [0,1024) vision chunk products, [1024,3072) text, [3072,4096) genomic
//     doubles @byte 65536: [0,32) vision-audit partials, [32,96) text-audit partials

typedef float v2f __attribute__((ext_vector_type(2)));
#define VFMA __builtin_elementwise_fma

__device__ __forceinline__ v2f vsplat(float s) { v2f r; r.x = s; r.y = s; return r; }

struct QF { float w, x, y, z; };
struct QP { v2f w, x, y, z; };     // two rows' quaternions, lane-parallel

__device__ __forceinline__ QF qmulf(const QF a, const QF b) {
    QF r;
    r.w = fmaf(a.w, b.w, -fmaf(a.x, b.x, fmaf(a.y, b.y, a.z * b.z)));
    r.x = fmaf(a.w, b.x, fmaf(a.x, b.w, fmaf(a.y, b.z, -(a.z * b.y))));
    r.y = fmaf(a.w, b.y, fmaf(a.y, b.w, fmaf(a.z, b.x, -(a.x * b.z))));
    r.z = fmaf(a.w, b.z, fmaf(a.x, b.y, fmaf(a.z, b.w, -(a.y * b.x))));
    return r;
}

__device__ __forceinline__ QP qmulp(const QP a, const QP b) {
    QP r;
    r.w = VFMA(a.w, b.w, -VFMA(a.x, b.x, VFMA(a.y, b.y, a.z * b.z)));
    r.x = VFMA(a.w, b.x, VFMA(a.x, b.w, VFMA(a.y, b.z, -(a.z * b.y))));
    r.y = VFMA(a.w, b.y, VFMA(a.y, b.w, VFMA(a.z, b.x, -(a.x * b.z))));
    r.z = VFMA(a.w, b.z, VFMA(a.x, b.y, VFMA(a.z, b.w, -(a.y * b.x))));
    return r;
}

// Ordered (non-commutative) 64-lane butterfly: lower lane's product on the left.
__device__ __forceinline__ QF wave_ordered_prod(QF p, int lane) {
    #pragma unroll
    for (int s = 1; s < 64; s <<= 1) {
        QF o;
        o.w = __shfl_xor(p.w, s, 64);
        o.x = __shfl_xor(p.x, s, 64);
        o.y = __shfl_xor(p.y, s, 64);
        o.z = __shfl_xor(p.z, s, 64);
        const bool hi = (lane & s) != 0;
        QF a = hi ? o : p;
        QF b = hi ? p : o;
        p = qmulf(a, b);
    }
    return p;
}

__device__ __forceinline__ QP wave_ordered_prod_p(QP p, int lane) {
    #pragma unroll
    for (int s = 1; s < 64; s <<= 1) {
        QP o;
        o.w.x = __shfl_xor(p.w.x, s, 64); o.w.y = __shfl_xor(p.w.y, s, 64);
        o.x.x = __shfl_xor(p.x.x, s, 64); o.x.y = __shfl_xor(p.x.y, s, 64);
        o.y.x = __shfl_xor(p.y.x, s, 64); o.y.y = __shfl_xor(p.y.y, s, 64);
        o.z.x = __shfl_xor(p.z.x, s, 64); o.z.y = __shfl_xor(p.z.y, s, 64);
        const bool hi = (lane & s) != 0;
        QP a, b;
        a.w = hi ? o.w : p.w; a.x = hi ? o.x : p.x; a.y = hi ? o.y : p.y; a.z = hi ? o.z : p.z;
        b.w = hi ? p.w : o.w; b.x = hi ? p.x : o.x; b.y = hi ? p.y : o.y; b.z = hi ? p.z : o.z;
        p = qmulp(a, b);
    }
    return p;
}

// Thread = half-chain (32 quats) of a row pair. Double-buffered staging,
// packed math (R14 inner loop), wave-uniform weight addresses.
template<int K, int BQ>
__device__ __forceinline__ void chain_hp(
    const float* __restrict__ X, const float* __restrict__ W,
    const float* __restrict__ bias, int rowBase,
    float* __restrict__ out4, float* __restrict__ sprod /* >= 512 floats */)
{
    constexpr int V = K + 1;
    constexpr int NB = 32 / BQ;
    const int t = threadIdx.x;        // 0..127
    const int lane = t & 63;
    const int h = t >> 6;             // wave-uniform half index
    const int rA = rowBase + lane;
    const int rB = rA + 64;
    const int i0 = h * 32;            // this wave's quat range

    v2f xv[K];
    #pragma unroll
    for (int k = 0; k < K; ++k) {
        xv[k].x = X[(size_t)rA * K + k];
        xv[k].y = X[(size_t)rB * K + k];
    }

    float4 A[BQ * V], Bb[BQ * V];
    QP p;
    float MA = 1.0f, MB = 1.0f, rrA = 0.0f, rrB = 0.0f;

    auto LOADB = [&](float4* dst, int bidx) {
        const int q0 = i0 + bidx * BQ;
        const float* bb = bias + 4 * q0;
        const float* wb = W + 4 * q0;
        #pragma unroll
        for (int j = 0; j < BQ; ++j) {
            dst[j * V + 0] = *(const float4*)(bb + 4 * j);
            #pragma unroll
            for (int k = 0; k < K; ++k)
                dst[j * V + 1 + k] = *(const float4*)(wb + k * DD + 4 * j);
        }
    };

    auto COMPUTE = [&](const float4* src, int bidx) {
        QP pb; v2f tt;
        #pragma unroll
        for (int j = 0; j < BQ; ++j) {
            const float4 b4 = src[j * V + 0];
            v2f l0 = vsplat(b4.x), l1 = vsplat(b4.y), l2 = vsplat(b4.z), l3 = vsplat(b4.w);
            #pragma unroll
            for (int k = 0; k < K; ++k) {
                const float4 w4 = src[j * V + 1 + k];
                l0 = VFMA(xv[k], vsplat(w4.x), l0);
                l1 = VFMA(xv[k], vsplat(w4.y), l1);
                l2 = VFMA(xv[k], vsplat(w4.z), l2);
                l3 = VFMA(xv[k], vsplat(w4.w), l3);
            }
            const v2f n2 = VFMA(l0, l0, VFMA(l1, l1, VFMA(l2, l2, l3 * l3)));
            rrA += __builtin_amdgcn_rsqf(n2.x);
            rrB += __builtin_amdgcn_rsqf(n2.y);
            QP q; q.w = l0; q.x = l1; q.y = l2; q.z = l3;
            if (j == 0) { pb = q; tt = n2; }
            else        { pb = qmulp(pb, q); tt *= n2; }
        }
        // exact power-of-2 rescale: m = tt*2^(-2*e2) in [1,4); M *= m
        const int e2A = ((__float_as_int(tt.x) >> 23) - 127) >> 1;
        const int e2B = ((__float_as_int(tt.y) >> 23) - 127) >> 1;
        const float scA = __int_as_float((127 - e2A) << 23);
        const float scB = __int_as_float((127 - e2B) << 23);
        MA *= tt.x * (scA * scA);
        MB *= tt.y * (scB * scB);
        v2f sc; sc.x = scA; sc.y = scB;
        pb.w *= sc; pb.x *= sc; pb.y *= sc; pb.z *= sc;
        if (bidx == 0) p = pb;
        else           p = qmulp(p, pb);
    };

    LOADB(A, 0);
    #pragma unroll
    for (int gg = 0; gg < NB / 2; ++gg) {
        LOADB(Bb, 2 * gg + 1);
        COMPUTE(A, 2 * gg);
        const int nb = (2 * gg + 2 < NB) ? (2 * gg + 2) : (NB - 1);
        LOADB(A, nb);
        COMPUTE(Bb, 2 * gg + 1);
    }

    // per-row segment normalize: / (sqrt(M) * (1 + eps*sum(1/n)))
    {
        const float invA = 1.0f / (sqrtf(MA) * fmaf(1e-8f, rrA, 1.0f));
        const float invB = 1.0f / (sqrtf(MB) * fmaf(1e-8f, rrB, 1.0f));
        v2f iv; iv.x = invA; iv.y = invB;
        p.w *= iv; p.x *= iv; p.y *= iv; p.z *= iv;
    }

    // join halves: wave1 -> LDS, wave0 multiplies on the right (quats 32..63 after 0..31)
    if (h == 1) {
        float* s8 = sprod + lane * 8;
        s8[0] = p.w.x; s8[1] = p.x.x; s8[2] = p.y.x; s8[3] = p.z.x;
        s8[4] = p.w.y; s8[5] = p.x.y; s8[6] = p.y.y; s8[7] = p.z.y;
    }
    __syncthreads();
    if (h == 0) {
        const float* s8 = sprod + lane * 8;
        QP o;
        o.w.x = s8[0]; o.x.x = s8[1]; o.y.x = s8[2]; o.z.x = s8[3];
        o.w.y = s8[4]; o.x.y = s8[5]; o.y.y = s8[6]; o.z.y = s8[7];
        p = qmulp(p, o);
        p = wave_ordered_prod_p(p, lane);
        if (lane == 0) {
            QF a = { p.w.x, p.x.x, p.y.x, p.z.x };   // rows 0..63 product
            QF b = { p.w.y, p.x.y, p.y.y, p.z.y };   // rows 64..127 product
            QF r = qmulf(a, b);
            float4 outv = { r.w, r.x, r.y, r.z };
            *(float4*)out4 = outv;
        }
    }
}

__global__ __launch_bounds__(128) void worker_kernel(
    const float* __restrict__ vis, const float* __restrict__ txt, const float* __restrict__ gen,
    const float* __restrict__ Wv, const float* __restrict__ bv,
    const float* __restrict__ Wt, const float* __restrict__ bt,
    const float* __restrict__ Wg, const float* __restrict__ bg,
    float* __restrict__ wsf, double* __restrict__ dws)
{
    __shared__ double sbuf[256];      // 2 KB: chain half-exchange / audit reduce
    float* sprod = (float*)sbuf;
    double* sred = sbuf;

    const int t  = threadIdx.x;
    const int id = blockIdx.x;

    if (id < 256) {
        const int b = id >> 5, chunk = id & 31;
        chain_hp<3, 4>(vis + (size_t)b * HW * 3, Wv, bv, chunk * 128,
                       wsf + (size_t)id * 4, sprod);
    } else if (id < 768) {
        const int i2 = id - 256;
        const int b = i2 >> 6, chunk = i2 & 63;
        chain_hp<1, 4>(txt + (size_t)b * LTXT, Wt, bt, chunk * 128,
                       wsf + 1024 + (size_t)i2 * 4, sprod);
    } else if (id < 1024) {
        const int i2 = id - 768;
        const int b = i2 >> 5, chunk = i2 & 31;
        chain_hp<4, 2>(gen + (size_t)b * GG * 4, Wg, bg, chunk * 128,
                       wsf + 3072 + (size_t)i2 * 4, sprod);
    } else if (id < 1056) {
        // ---------------- vision audit: thread = row ----------------
        const int aid = id - 1024;
        const int r = aid * 128 + t;          // 0..4095
        float gx[8], gy[8], gz[8];
        {
            float vx[8], vy[8], vz[8];
            #pragma unroll
            for (int b = 0; b < 8; ++b) {
                const size_t base = ((size_t)b * HW + r) * 3;
                vx[b] = vis[base]; vy[b] = vis[base+1]; vz[b] = vis[base+2];
            }
            #pragma unroll
            for (int b = 0; b < 8; ++b) {
                if (b == 0)      { gx[b] = vx[1]-vx[0];  gy[b] = vy[1]-vy[0];  gz[b] = vz[1]-vz[0]; }
                else if (b == 7) { gx[b] = vx[7]-vx[6];  gy[b] = vy[7]-vy[6];  gz[b] = vz[7]-vz[6]; }
                else             { gx[b] = (vx[b+1]-vx[b-1])*0.5f; gy[b] = (vy[b+1]-vy[b-1])*0.5f; gz[b] = (vz[b+1]-vz[b-1])*0.5f; }
            }
        }
        double acc = 0.0;
        #pragma unroll 4
        for (int i = 0; i < 64; ++i) {
            const float4 a0 = *(const float4*)(Wv + 4*i);
            const float4 a1 = *(const float4*)(Wv + DD + 4*i);
            const float4 a2 = *(const float4*)(Wv + 2*DD + 4*i);
            const float wq0 = a0.x + a0.y + a0.z + a0.w;
            const float wq1 = a1.x + a1.y + a1.z + a1.w;
            const float wq2 = a2.x + a2.y + a2.z + a2.w;
            float acc8 = 0.0f;
            #pragma unroll
            for (int b = 0; b < 8; ++b)
                acc8 += fabsf(fmaf(gx[b], wq0, fmaf(gy[b], wq1, gz[b] * wq2)));
            acc += (double)acc8;
        }
        sred[t] = acc;
        __syncthreads();
        for (int off = 64; off > 0; off >>= 1) {
            if (t < off) sred[t] += sred[t + off];
            __syncthreads();
        }
        if (t == 0) dws[aid] = sred[0];
    } else {
        // ---------------- text audit (gradient factor) ----------------
        const int aid = id - 1056;
        const int l = aid * 128 + t;          // 0..8191
        float tv[8];
        #pragma unroll
        for (int b = 0; b < 8; ++b) tv[b] = txt[(size_t)b * LTXT + l];
        double acc = 0.0;
        #pragma unroll
        for (int b = 0; b < 8; ++b) {
            float gb;
            if (b == 0)      gb = tv[1] - tv[0];
            else if (b == 7) gb = tv[7] - tv[6];
            else             gb = (tv[b+1] - tv[b-1]) * 0.5f;
            acc += (double)fabsf(gb);
        }
        sred[t] = acc;
        __syncthreads();
        for (int off = 64; off > 0; off >>= 1) {
            if (t < off) sred[t] += sred[t + off];
            __syncthreads();
        }
        if (t == 0) dws[32 + aid] = sred[0];
    }
}

__global__ __launch_bounds__(256) void finalize_kernel(
    const float* __restrict__ vis, const float* __restrict__ txt, const float* __restrict__ gen,
    const float* __restrict__ Wv, const float* __restrict__ bv,
    const float* __restrict__ Wt, const float* __restrict__ bt,
    const float* __restrict__ Wg, const float* __restrict__ bg,
    const float* __restrict__ wsf, const double* __restrict__ dws,
    float* __restrict__ out)
{
    __shared__ float sphi[24];      // phi[m][b]
    __shared__ double sred[256];
    __shared__ double s_sumv, s_sumt, s_sumw;
    const int t = threadIdx.x;
    const int lane = t & 63, w = t >> 6;

    // each wave handles 6 (m,b) pairs; lane-per-chunk ordered butterfly combine
    #pragma unroll
    for (int j = 0; j < 6; ++j) {
        const int pair = w * 6 + j;          // 0..23
        const int m = pair >> 3, b = pair & 7;
        const int nch = (m == 1) ? 64 : 32;
        const float* base = wsf + ((m == 0) ? 0 : (m == 1) ? 1024 : 3072) + (size_t)b * nch * 4;
        QF p = { 1.0f, 0.0f, 0.0f, 0.0f };
        if (lane < nch) {
            const float4 c0 = *(const float4*)(base + lane * 4);
            p = { c0.x, c0.y, c0.z, c0.w };
        }
        p = wave_ordered_prod(p, lane);
        if (lane == 0) {
            float lat[4];
            if (m == 0) {
                const float x0 = vis[(size_t)b*HW*3], x1 = vis[(size_t)b*HW*3+1], x2 = vis[(size_t)b*HW*3+2];
                #pragma unroll
                for (int c = 0; c < 4; ++c)
                    lat[c] = fmaf(x0, Wv[c], fmaf(x1, Wv[DD+c], fmaf(x2, Wv[2*DD+c], bv[c])));
            } else if (m == 1) {
                const float x0 = txt[(size_t)b*LTXT];
                #pragma unroll
                for (int c = 0; c < 4; ++c) lat[c] = fmaf(x0, Wt[c], bt[c]);
            } else {
                const float x0 = gen[(size_t)b*GG*4], x1 = gen[(size_t)b*GG*4+1],
                            x2 = gen[(size_t)b*GG*4+2], x3 = gen[(size_t)b*GG*4+3];
                #pragma unroll
                for (int c = 0; c < 4; ++c)
                    lat[c] = fmaf(x0, Wg[c], fmaf(x1, Wg[DD+c], fmaf(x2, Wg[2*DD+c], fmaf(x3, Wg[3*DD+c], bg[c]))));
            }
            const float n = sqrtf(fmaf(lat[0], lat[0], fmaf(lat[1], lat[1], fmaf(lat[2], lat[2], lat[3] * lat[3]))));
            const float inv = 1.0f / (n + 1e-8f);
            QF q0 = { lat[0]*inv, lat[1]*inv, lat[2]*inv, lat[3]*inv };
            p = qmulf(p, q0);
            float ww = p.w;
            ww = fminf(1.0f, fmaxf(-1.0f, ww));
            sphi[pair] = 2.0f * acosf(ww);
        }
    }
    __syncthreads();

    // vision audit sum (32 partials)
    sred[t] = (t < 32) ? dws[t] : 0.0; __syncthreads();
    for (int off = 128; off > 0; off >>= 1) { if (t < off) sred[t] += sred[t+off]; __syncthreads(); }
    if (t == 0) s_sumv = sred[0];
    __syncthreads();

    // text audit sum (64 partials)
    sred[t] = (t < 64) ? dws[32 + t] : 0.0; __syncthreads();
    for (int off = 128; off > 0; off >>= 1) { if (t < off) sred[t] += sred[t+off]; __syncthreads(); }
    if (t == 0) s_sumt = sred[0];
    __syncthreads();

    // sum_i |wtq_i|
    double aw = 0.0;
    if (t < 64) {
        const int d0 = 4 * t;
        aw = (double)fabsf(Wt[d0] + Wt[d0+1] + Wt[d0+2] + Wt[d0+3]);
    }
    sred[t] = aw; __syncthreads();
    for (int off = 128; off > 0; off >>= 1) { if (t < off) sred[t] += sred[t+off]; __syncthreads(); }
    if (t == 0) s_sumw = sred[0];
    __syncthreads();

    if (t == 0) {
        float mv = 0.0f, mt = 0.0f;
        for (int b = 0; b < 8; ++b) { mv += sphi[b]; mt += sphi[8 + b]; }
        mv *= 0.125f; mt *= 0.125f;
        const float interf = fabsf(mv - mt);
        for (int b = 0; b < 8; ++b)
            out[b] = expf(-fabsf(sphi[16 + b] - interf));
        out[8]  = interf;
        out[9]  = (float)(s_sumv / 2097152.0);            // 8 * 4096 * 64
        out[10] = (float)(s_sumt * s_sumw / 4194304.0);   // 8 * 8192 * 64
    }
}

extern "C" void kernel_launch(void* const* d_in, const int* in_sizes, int n_in,
                              void* d_out, int out_size, void* d_ws, size_t ws_size,
                              hipStream_t stream) {
    (void)in_sizes; (void)n_in; (void)out_size; (void)ws_size;
    const float* vis = (const float*)d_in[0];
    const float* txt = (const float*)d_in[1];
    const float* gen = (const float*)d_in[2];
    const float* Wv  = (const float*)d_in[3];
    const float* bv  = (const float*)d_in[4];
    const float* Wt  = (const float*)d_in[5];
    const float* bt  = (const float*)d_in[6];
    const float* Wg  = (const float*)d_in[7];
    const float* bg  = (const float*)d_in[8];
    float*  wsf = (float*)d_ws;
    double* dws = (double*)((char*)d_ws + 65536);
    float*  out = (float*)d_out;

    hipLaunchKernelGGL(worker_kernel, dim3(1120), dim3(128), 0, stream,
                       vis, txt, gen, Wv, bv, Wt, bt, Wg, bg, wsf, dws);
    hipLaunchKernelGGL(finalize_kernel, dim3(1), dim3(256), 0, stream,
                       vis, txt, gen, Wv, bv, Wt, bt, Wg, bg, wsf, dws, out);
}

// Round 16
// 33.020 us; speedup vs baseline: 1.0070x; 1.0070x over previous
//
#include <hip/hip_runtime.h>
#include <math.h>

// Problem constants (from setup_inputs)
#define BB 8
#define HW 4096
#define LTXT 8192
#define GG 4096
#define DD 256

// Worker grid: 608 blocks x 128 threads (R14 structure).
// Chain blocks: thread t owns row pair (rowBase+t, rowBase+128+t) packed in v2f
// lanes (R14 zero-swizzle packing). NEW vs R14: the 64-quat spine is split into
// TWO INDEPENDENT sub-chains (quats 0..31 -> p0, 32..63 -> p1) computed in the
// same loop with interleaved double-buffered loads -> ILP=2 covers qmulp dep
// latency at 1 wave/SIMD. Combined in order at the end: p = p0 * p1.
//   [0,128)    vision chains:  b = id/16,        chunk = id%16  (256 rows)
//   [128,384)  text chains:    b = (id-128)/32,  chunk = %32
//   [384,512)  genomic chains: b = (id-384)/16,  chunk = %16
//   [512,544)  vision audit (32 blocks, thread = row)
//   [544,608)  text audit (64 blocks, thread = position)
//
// Normalization (validated family, R13/R14 absmax 0): multiply RAW quats; per
// batch exact 2^-e2 rescale (exponent extract), accumulate mantissa product M
// and rr = sum rsq(n2); once per sub-chain: divide by sqrt(M)*(1 + 1e-8f*rr).
//
// ws: floats [0,512) vision chunk products, [512,1536) text, [1536,2048) genomic
//     doubles @byte 65536: [0,32) vision-audit partials, [32,96) text-audit partials

typedef float v2f __attribute__((ext_vector_type(2)));
#define VFMA __builtin_elementwise_fma

__device__ __forceinline__ v2f vsplat(float s) { v2f r; r.x = s; r.y = s; return r; }

struct QF { float w, x, y, z; };
struct QP { v2f w, x, y, z; };     // two rows' quaternions, lane-parallel

__device__ __forceinline__ QF qmulf(const QF a, const QF b) {
    QF r;
    r.w = fmaf(a.w, b.w, -fmaf(a.x, b.x, fmaf(a.y, b.y, a.z * b.z)));
    r.x = fmaf(a.w, b.x, fmaf(a.x, b.w, fmaf(a.y, b.z, -(a.z * b.y))));
    r.y = fmaf(a.w, b.y, fmaf(a.y, b.w, fmaf(a.z, b.x, -(a.x * b.z))));
    r.z = fmaf(a.w, b.z, fmaf(a.x, b.y, fmaf(a.z, b.w, -(a.y * b.x))));
    return r;
}

__device__ __forceinline__ QP qmulp(const QP a, const QP b) {
    QP r;
    r.w = VFMA(a.w, b.w, -VFMA(a.x, b.x, VFMA(a.y, b.y, a.z * b.z)));
    r.x = VFMA(a.w, b.x, VFMA(a.x, b.w, VFMA(a.y, b.z, -(a.z * b.y))));
    r.y = VFMA(a.w, b.y, VFMA(a.y, b.w, VFMA(a.z, b.x, -(a.x * b.z))));
    r.z = VFMA(a.w, b.z, VFMA(a.x, b.y, VFMA(a.z, b.w, -(a.y * b.x))));
    return r;
}

// Ordered (non-commutative) 64-lane butterfly: lower lane's product on the left.
__device__ __forceinline__ QF wave_ordered_prod(QF p, int lane) {
    #pragma unroll
    for (int s = 1; s < 64; s <<= 1) {
        QF o;
        o.w = __shfl_xor(p.w, s, 64);
        o.x = __shfl_xor(p.x, s, 64);
        o.y = __shfl_xor(p.y, s, 64);
        o.z = __shfl_xor(p.z, s, 64);
        const bool hi = (lane & s) != 0;
        QF a = hi ? o : p;
        QF b = hi ? p : o;
        p = qmulf(a, b);
    }
    return p;
}

__device__ __forceinline__ QP wave_ordered_prod_p(QP p, int lane) {
    #pragma unroll
    for (int s = 1; s < 64; s <<= 1) {
        QP o;
        o.w.x = __shfl_xor(p.w.x, s, 64); o.w.y = __shfl_xor(p.w.y, s, 64);
        o.x.x = __shfl_xor(p.x.x, s, 64); o.x.y = __shfl_xor(p.x.y, s, 64);
        o.y.x = __shfl_xor(p.y.x, s, 64); o.y.y = __shfl_xor(p.y.y, s, 64);
        o.z.x = __shfl_xor(p.z.x, s, 64); o.z.y = __shfl_xor(p.z.y, s, 64);
        const bool hi = (lane & s) != 0;
        QP a, b;
        a.w = hi ? o.w : p.w; a.x = hi ? o.x : p.x; a.y = hi ? o.y : p.y; a.z = hi ? o.z : p.z;
        b.w = hi ? p.w : o.w; b.x = hi ? p.x : o.x; b.y = hi ? p.y : o.y; b.z = hi ? p.z : o.z;
        p = qmulp(a, b);
    }
    return p;
}

// Thread = row pair, TWO independent 32-quat sub-chains (ILP=2).
template<int K, int BQ>
__device__ __forceinline__ void chain_dual(
    const float* __restrict__ X, const float* __restrict__ W,
    const float* __restrict__ bias, int rowBase,
    float* __restrict__ out4, float* __restrict__ sprod)
{
    constexpr int V = K + 1;
    constexpr int NB2 = 32 / BQ;      // batches per sub-chain (even)
    const int t = threadIdx.x;        // 0..127
    const int rA = rowBase + t;
    const int rB = rA + 128;

    v2f xv[K];
    #pragma unroll
    for (int k = 0; k < K; ++k) {
        xv[k].x = X[(size_t)rA * K + k];
        xv[k].y = X[(size_t)rB * K + k];
    }

    float4 A0[BQ * V], B0[BQ * V], A1[BQ * V], B1[BQ * V];
    QP p0, p1;
    float M0A = 1.0f, M0B = 1.0f, rr0A = 0.0f, rr0B = 0.0f;
    float M1A = 1.0f, M1B = 1.0f, rr1A = 0.0f, rr1B = 0.0f;

    auto LOADB = [&](float4* dst, int half, int bidx) {
        const int q0 = half * 32 + bidx * BQ;
        const float* bb = bias + 4 * q0;
        const float* wb = W + 4 * q0;
        #pragma unroll
        for (int j = 0; j < BQ; ++j) {
            dst[j * V + 0] = *(const float4*)(bb + 4 * j);
            #pragma unroll
            for (int k = 0; k < K; ++k)
                dst[j * V + 1 + k] = *(const float4*)(wb + k * DD + 4 * j);
        }
    };

    auto COMPUTE = [&](const float4* src, QP& p, float& MA, float& MB,
                       float& rrA, float& rrB, int bidx) {
        QP pb; v2f tt;
        #pragma unroll
        for (int j = 0; j < BQ; ++j) {
            const float4 b4 = src[j * V + 0];
            v2f l0 = vsplat(b4.x), l1 = vsplat(b4.y), l2 = vsplat(b4.z), l3 = vsplat(b4.w);
            #pragma unroll
            for (int k = 0; k < K; ++k) {
                const float4 w4 = src[j * V + 1 + k];
                l0 = VFMA(xv[k], vsplat(w4.x), l0);
                l1 = VFMA(xv[k], vsplat(w4.y), l1);
                l2 = VFMA(xv[k], vsplat(w4.z), l2);
                l3 = VFMA(xv[k], vsplat(w4.w), l3);
            }
            const v2f n2 = VFMA(l0, l0, VFMA(l1, l1, VFMA(l2, l2, l3 * l3)));
            rrA += __builtin_amdgcn_rsqf(n2.x);
            rrB += __builtin_amdgcn_rsqf(n2.y);
            QP q; q.w = l0; q.x = l1; q.y = l2; q.z = l3;
            if (j == 0) { pb = q; tt = n2; }
            else        { pb = qmulp(pb, q); tt *= n2; }
        }
        // exact power-of-2 rescale: m = tt*2^(-2*e2) in [1,4); M *= m
        const int e2A = ((__float_as_int(tt.x) >> 23) - 127) >> 1;
        const int e2B = ((__float_as_int(tt.y) >> 23) - 127) >> 1;
        const float scA = __int_as_float((127 - e2A) << 23);
        const float scB = __int_as_float((127 - e2B) << 23);
        MA *= tt.x * (scA * scA);
        MB *= tt.y * (scB * scB);
        v2f sc; sc.x = scA; sc.y = scB;
        pb.w *= sc; pb.x *= sc; pb.y *= sc; pb.z *= sc;
        if (bidx == 0) p = pb;
        else           p = qmulp(p, pb);
    };

    LOADB(A0, 0, 0); LOADB(A1, 1, 0);
    for (int gg = 0; gg < NB2 / 2; ++gg) {
        LOADB(B0, 0, 2 * gg + 1); LOADB(B1, 1, 2 * gg + 1);
        COMPUTE(A0, p0, M0A, M0B, rr0A, rr0B, 2 * gg);
        COMPUTE(A1, p1, M1A, M1B, rr1A, rr1B, 2 * gg);
        const int nb = (2 * gg + 2 < NB2) ? (2 * gg + 2) : (NB2 - 1);
        LOADB(A0, 0, nb); LOADB(A1, 1, nb);
        COMPUTE(B0, p0, M0A, M0B, rr0A, rr0B, 2 * gg + 1);
        COMPUTE(B1, p1, M1A, M1B, rr1A, rr1B, 2 * gg + 1);
    }

    // per-sub-chain normalize, then join in order: quats 0..31 then 32..63
    {
        v2f iv0, iv1;
        iv0.x = 1.0f / (sqrtf(M0A) * fmaf(1e-8f, rr0A, 1.0f));
        iv0.y = 1.0f / (sqrtf(M0B) * fmaf(1e-8f, rr0B, 1.0f));
        iv1.x = 1.0f / (sqrtf(M1A) * fmaf(1e-8f, rr1A, 1.0f));
        iv1.y = 1.0f / (sqrtf(M1B) * fmaf(1e-8f, rr1B, 1.0f));
        p0.w *= iv0; p0.x *= iv0; p0.y *= iv0; p0.z *= iv0;
        p1.w *= iv1; p1.x *= iv1; p1.y *= iv1; p1.z *= iv1;
    }
    QP p = qmulp(p0, p1);

    const int lane = t & 63;
    p = wave_ordered_prod_p(p, lane);

    const int w = t >> 6;             // 0..1
    if (lane == 0) {
        float* s8 = sprod + w * 8;
        s8[0] = p.w.x; s8[1] = p.x.x; s8[2] = p.y.x; s8[3] = p.z.x;   // A-half
        s8[4] = p.w.y; s8[5] = p.x.y; s8[6] = p.y.y; s8[7] = p.z.y;   // B-half
    }
    __syncthreads();
    if (t == 0) {
        // order: rows 0..63 (w0 A), 64..127 (w1 A), 128..191 (w0 B), 192..255 (w1 B)
        QF A0q = { sprod[0], sprod[1], sprod[2], sprod[3] };
        QF A1q = { sprod[8], sprod[9], sprod[10], sprod[11] };
        QF B0q = { sprod[4], sprod[5], sprod[6], sprod[7] };
        QF B1q = { sprod[12], sprod[13], sprod[14], sprod[15] };
        QF r = qmulf(qmulf(qmulf(A0q, A1q), B0q), B1q);
        float4 outv = { r.w, r.x, r.y, r.z };
        *(float4*)out4 = outv;
    }
}

__global__ __launch_bounds__(128, 1) void worker_kernel(
    const float* __restrict__ vis, const float* __restrict__ txt, const float* __restrict__ gen,
    const float* __restrict__ Wv, const float* __restrict__ bv,
    const float* __restrict__ Wt, const float* __restrict__ bt,
    const float* __restrict__ Wg, const float* __restrict__ bg,
    float* __restrict__ wsf, double* __restrict__ dws)
{
    __shared__ double sred[128];
    float* sprod = (float*)sred;

    const int t  = threadIdx.x;
    const int id = blockIdx.x;

    if (id < 128) {
        const int b = id >> 4, chunk = id & 15;
        chain_dual<3, 2>(vis + (size_t)b * HW * 3, Wv, bv, chunk * 256,
                         wsf + (size_t)id * 4, sprod);
    } else if (id < 384) {
        const int i2 = id - 128;
        const int b = i2 >> 5, chunk = i2 & 31;
        chain_dual<1, 4>(txt + (size_t)b * LTXT, Wt, bt, chunk * 256,
                         wsf + 512 + (size_t)i2 * 4, sprod);
    } else if (id < 512) {
        const int i2 = id - 384;
        const int b = i2 >> 4, chunk = i2 & 15;
        chain_dual<4, 2>(gen + (size_t)b * GG * 4, Wg, bg, chunk * 256,
                         wsf + 1536 + (size_t)i2 * 4, sprod);
    } else if (id < 544) {
        // ---------------- vision audit: thread = row ----------------
        const int aid = id - 512;
        const int r = aid * 128 + t;          // 0..4095
        float gx[8], gy[8], gz[8];
        {
            float vx[8], vy[8], vz[8];
            #pragma unroll
            for (int b = 0; b < 8; ++b) {
                const size_t base = ((size_t)b * HW + r) * 3;
                vx[b] = vis[base]; vy[b] = vis[base+1]; vz[b] = vis[base+2];
            }
            #pragma unroll
            for (int b = 0; b < 8; ++b) {
                if (b == 0)      { gx[b] = vx[1]-vx[0];  gy[b] = vy[1]-vy[0];  gz[b] = vz[1]-vz[0]; }
                else if (b == 7) { gx[b] = vx[7]-vx[6];  gy[b] = vy[7]-vy[6];  gz[b] = vz[7]-vz[6]; }
                else             { gx[b] = (vx[b+1]-vx[b-1])*0.5f; gy[b] = (vy[b+1]-vy[b-1])*0.5f; gz[b] = (vz[b+1]-vz[b-1])*0.5f; }
            }
        }
        double acc = 0.0;
        #pragma unroll 4
        for (int i = 0; i < 64; ++i) {
            const float4 a0 = *(const float4*)(Wv + 4*i);
            const float4 a1 = *(const float4*)(Wv + DD + 4*i);
            const float4 a2 = *(const float4*)(Wv + 2*DD + 4*i);
            const float wq0 = a0.x + a0.y + a0.z + a0.w;
            const float wq1 = a1.x + a1.y + a1.z + a1.w;
            const float wq2 = a2.x + a2.y + a2.z + a2.w;
            float acc8 = 0.0f;
            #pragma unroll
            for (int b = 0; b < 8; ++b)
                acc8 += fabsf(fmaf(gx[b], wq0, fmaf(gy[b], wq1, gz[b] * wq2)));
            acc += (double)acc8;
        }
        sred[t] = acc;
        __syncthreads();
        for (int off = 64; off > 0; off >>= 1) {
            if (t < off) sred[t] += sred[t + off];
            __syncthreads();
        }
        if (t == 0) dws[aid] = sred[0];
    } else {
        // ---------------- text audit (gradient factor) ----------------
        const int aid = id - 544;
        const int l = aid * 128 + t;          // 0..8191
        float tv[8];
        #pragma unroll
        for (int b = 0; b < 8; ++b) tv[b] = txt[(size_t)b * LTXT + l];
        double acc = 0.0;
        #pragma unroll
        for (int b = 0; b < 8; ++b) {
            float gb;
            if (b == 0)      gb = tv[1] - tv[0];
            else if (b == 7) gb = tv[7] - tv[6];
            else             gb = (tv[b+1] - tv[b-1]) * 0.5f;
            acc += (double)fabsf(gb);
        }
        sred[t] = acc;
        __syncthreads();
        for (int off = 64; off > 0; off >>= 1) {
            if (t < off) sred[t] += sred[t + off];
            __syncthreads();
        }
        if (t == 0) dws[32 + aid] = sred[0];
    }
}

__global__ __launch_bounds__(256) void finalize_kernel(
    const float* __restrict__ vis, const float* __restrict__ txt, const float* __restrict__ gen,
    const float* __restrict__ Wv, const float* __restrict__ bv,
    const float* __restrict__ Wt, const float* __restrict__ bt,
    const float* __restrict__ Wg, const float* __restrict__ bg,
    const float* __restrict__ wsf, const double* __restrict__ dws,
    float* __restrict__ out)
{
    __shared__ float sphi[24];      // phi[m][b]
    __shared__ double sred[256];
    __shared__ double s_sumv, s_sumt, s_sumw;
    const int t = threadIdx.x;
    const int lane = t & 63, w = t >> 6;

    // each wave handles 6 (m,b) pairs; lane-per-chunk ordered butterfly combine
    #pragma unroll
    for (int j = 0; j < 6; ++j) {
        const int pair = w * 6 + j;          // 0..23
        const int m = pair >> 3, b = pair & 7;
        const int nch = (m == 1) ? 32 : 16;
        const float* base = wsf + ((m == 0) ? 0 : (m == 1) ? 512 : 1536) + (size_t)b * nch * 4;
        QF p = { 1.0f, 0.0f, 0.0f, 0.0f };
        if (lane < nch) {
            const float4 c0 = *(const float4*)(base + lane * 4);
            p = { c0.x, c0.y, c0.z, c0.w };
        }
        p = wave_ordered_prod(p, lane);
        if (lane == 0) {
            float lat[4];
            if (m == 0) {
                const float x0 = vis[(size_t)b*HW*3], x1 = vis[(size_t)b*HW*3+1], x2 = vis[(size_t)b*HW*3+2];
                #pragma unroll
                for (int c = 0; c < 4; ++c)
                    lat[c] = fmaf(x0, Wv[c], fmaf(x1, Wv[DD+c], fmaf(x2, Wv[2*DD+c], bv[c])));
            } else if (m == 1) {
                const float x0 = txt[(size_t)b*LTXT];
                #pragma unroll
                for (int c = 0; c < 4; ++c) lat[c] = fmaf(x0, Wt[c], bt[c]);
            } else {
                const float x0 = gen[(size_t)b*GG*4], x1 = gen[(size_t)b*GG*4+1],
                            x2 = gen[(size_t)b*GG*4+2], x3 = gen[(size_t)b*GG*4+3];
                #pragma unroll
                for (int c = 0; c < 4; ++c)
                    lat[c] = fmaf(x0, Wg[c], fmaf(x1, Wg[DD+c], fmaf(x2, Wg[2*DD+c], fmaf(x3, Wg[3*DD+c], bg[c]))));
            }
            const float n = sqrtf(fmaf(lat[0], lat[0], fmaf(lat[1], lat[1], fmaf(lat[2], lat[2], lat[3] * lat[3]))));
            const float inv = 1.0f / (n + 1e-8f);
            QF q0 = { lat[0]*inv, lat[1]*inv, lat[2]*inv, lat[3]*inv };
            p = qmulf(p, q0);
            float ww = p.w;
            ww = fminf(1.0f, fmaxf(-1.0f, ww));
            sphi[pair] = 2.0f * acosf(ww);
        }
    }
    __syncthreads();

    // vision audit sum (32 partials)
    sred[t] = (t < 32) ? dws[t] : 0.0; __syncthreads();
    for (int off = 128; off > 0; off >>= 1) { if (t < off) sred[t] += sred[t+off]; __syncthreads(); }
    if (t == 0) s_sumv = sred[0];
    __syncthreads();

    // text audit sum (64 partials)
    sred[t] = (t < 64) ? dws[32 + t] : 0.0; __syncthreads();
    for (int off = 128; off > 0; off >>= 1) { if (t < off) sred[t] += sred[t+off]; __syncthreads(); }
    if (t == 0) s_sumt = sred[0];
    __syncthreads();

    // sum_i |wtq_i|
    double aw = 0.0;
    if (t < 64) {
        const int d0 = 4 * t;
        aw = (double)fabsf(Wt[d0] + Wt[d0+1] + Wt[d0+2] + Wt[d0+3]);
    }
    sred[t] = aw; __syncthreads();
    for (int off = 128; off > 0; off >>= 1) { if (t < off) sred[t] += sred[t+off]; __syncthreads(); }
    if (t == 0) s_sumw = sred[0];
    __syncthreads();

    if (t == 0) {
        float mv = 0.0f, mt = 0.0f;
        for (int b = 0; b < 8; ++b) { mv += sphi[b]; mt += sphi[8 + b]; }
        mv *= 0.125f; mt *= 0.125f;
        const float interf = fabsf(mv - mt);
        for (int b = 0; b < 8; ++b)
            out[b] = expf(-fabsf(sphi[16 + b] - interf));
        out[8]  = interf;
        out[9]  = (float)(s_sumv / 2097152.0);            // 8 * 4096 * 64
        out[10] = (float)(s_sumt * s_sumw / 4194304.0);   // 8 * 8192 * 64
    }
}

extern "C" void kernel_launch(void* const* d_in, const int* in_sizes, int n_in,
                              void* d_out, int out_size, void* d_ws, size_t ws_size,
                              hipStream_t stream) {
    (void)in_sizes; (void)n_in; (void)out_size; (void)ws_size;
    const float* vis = (const float*)d_in[0];
    const float* txt = (const float*)d_in[1];
    const float* gen = (const float*)d_in[2];
    const float* Wv  = (const float*)d_in[3];
    const float* bv  = (const float*)d_in[4];
    const float* Wt  = (const float*)d_in[5];
    const float* bt  = (const float*)d_in[6];
    const float* Wg  = (const float*)d_in[7];
    const float* bg  = (const float*)d_in[8];
    float*  wsf = (float*)d_ws;
    double* dws = (double*)((char*)d_ws + 65536);
    float*  out = (float*)d_out;

    hipLaunchKernelGGL(worker_kernel, dim3(608), dim3(128), 0, stream,
                       vis, txt, gen, Wv, bv, Wt, bt, Wg, bg, wsf, dws);
    hipLaunchKernelGGL(finalize_kernel, dim3(1), dim3(256), 0, stream,
                       vis, txt, gen, Wv, bv, Wt, bt, Wg, bg, wsf, dws, out);
}

// Round 17
// 30.404 us; speedup vs baseline: 1.0936x; 1.0860x over previous
//
#include <hip/hip_runtime.h>
#include <math.h>

// Problem constants (from setup_inputs)
#define BB 8
#define HW 4096
#define LTXT 8192
#define GG 4096
#define DD 256

// Worker grid: 608 blocks x 128 threads.
// Chain blocks: thread t handles TWO rows (rowBase+t, rowBase+128+t) packed in
// the two lanes of float2 ext-vectors -> v_pk_fma_f32 packed math (2 FMA/instr)
// with ZERO swizzles (rows never interact), and all weight loads shared.
//   [0,128)    vision chains:  b = id/16,        chunk = id%16  (256 rows)
//   [128,384)  text chains:    b = (id-128)/32,  chunk = %32
//   [384,512)  genomic chains: b = (id-384)/16,  chunk = %16
//   [512,544)  vision audit (32 blocks, thread = row)
//   [544,608)  text audit (64 blocks, thread = position)
//
// Normalization (validated family, R13 absmax 0): multiply RAW quats; per batch
// rescale by exact 2^-e2 (exponent extract) to avoid under/overflow, accumulate
// mantissa product M and rr = sum rsq(n2); per ROW once: divide by
// sqrt(M) * (1 + 1e-8f * rr)  [= prod(n_i + 1e-8f) to 2nd order ~1e-13].
//
// ws: floats [0,512) vision chunk products, [512,1536) text, [1536,2048) genomic
//     doubles @byte 65536: [0,32) vision-audit partials, [32,96) text-audit partials

typedef float v2f __attribute__((ext_vector_type(2)));
#define VFMA __builtin_elementwise_fma

__device__ __forceinline__ v2f vsplat(float s) { v2f r; r.x = s; r.y = s; return r; }

struct QF { float w, x, y, z; };
struct QP { v2f w, x, y, z; };     // two rows' quaternions, lane-parallel

__device__ __forceinline__ QF qmulf(const QF a, const QF b) {
    QF r;
    r.w = fmaf(a.w, b.w, -fmaf(a.x, b.x, fmaf(a.y, b.y, a.z * b.z)));
    r.x = fmaf(a.w, b.x, fmaf(a.x, b.w, fmaf(a.y, b.z, -(a.z * b.y))));
    r.y = fmaf(a.w, b.y, fmaf(a.y, b.w, fmaf(a.z, b.x, -(a.x * b.z))));
    r.z = fmaf(a.w, b.z, fmaf(a.x, b.y, fmaf(a.z, b.w, -(a.y * b.x))));
    return r;
}

__device__ __forceinline__ QP qmulp(const QP a, const QP b) {
    QP r;
    r.w = VFMA(a.w, b.w, -VFMA(a.x, b.x, VFMA(a.y, b.y, a.z * b.z)));
    r.x = VFMA(a.w, b.x, VFMA(a.x, b.w, VFMA(a.y, b.z, -(a.z * b.y))));
    r.y = VFMA(a.w, b.y, VFMA(a.y, b.w, VFMA(a.z, b.x, -(a.x * b.z))));
    r.z = VFMA(a.w, b.z, VFMA(a.x, b.y, VFMA(a.z, b.w, -(a.y * b.x))));
    return r;
}

// Ordered (non-commutative) 64-lane butterfly: lower lane's product on the left.
__device__ __forceinline__ QF wave_ordered_prod(QF p, int lane) {
    #pragma unroll
    for (int s = 1; s < 64; s <<= 1) {
        QF o;
        o.w = __shfl_xor(p.w, s, 64);
        o.x = __shfl_xor(p.x, s, 64);
        o.y = __shfl_xor(p.y, s, 64);
        o.z = __shfl_xor(p.z, s, 64);
        const bool hi = (lane & s) != 0;
        QF a = hi ? o : p;
        QF b = hi ? p : o;
        p = qmulf(a, b);
    }
    return p;
}

__device__ __forceinline__ QP wave_ordered_prod_p(QP p, int lane) {
    #pragma unroll
    for (int s = 1; s < 64; s <<= 1) {
        QP o;
        o.w.x = __shfl_xor(p.w.x, s, 64); o.w.y = __shfl_xor(p.w.y, s, 64);
        o.x.x = __shfl_xor(p.x.x, s, 64); o.x.y = __shfl_xor(p.x.y, s, 64);
        o.y.x = __shfl_xor(p.y.x, s, 64); o.y.y = __shfl_xor(p.y.y, s, 64);
        o.z.x = __shfl_xor(p.z.x, s, 64); o.z.y = __shfl_xor(p.z.y, s, 64);
        const bool hi = (lane & s) != 0;
        QP a, b;
        a.w = hi ? o.w : p.w; a.x = hi ? o.x : p.x; a.y = hi ? o.y : p.y; a.z = hi ? o.z : p.z;
        b.w = hi ? p.w : o.w; b.x = hi ? p.x : o.x; b.y = hi ? p.y : o.y; b.z = hi ? p.z : o.z;
        p = qmulp(a, b);
    }
    return p;
}

// Thread = two rows. Double-buffered weight staging (R5 form), packed math.
template<int K, int BQ>
__device__ __forceinline__ void chain_pair(
    const float* __restrict__ X, const float* __restrict__ W,
    const float* __restrict__ bias, int rowBase,
    float* __restrict__ out4, float* sprod)
{
    constexpr int V = K + 1;
    constexpr int NB = 64 / BQ;
    const int t = threadIdx.x;        // 0..127
    const int rA = rowBase + t;
    const int rB = rA + 128;

    v2f xv[K];
    #pragma unroll
    for (int k = 0; k < K; ++k) {
        xv[k].x = X[(size_t)rA * K + k];
        xv[k].y = X[(size_t)rB * K + k];
    }

    float4 A[BQ * V], Bb[BQ * V];
    QP p;
    float MA = 1.0f, MB = 1.0f, rrA = 0.0f, rrB = 0.0f;

    auto LOADB = [&](float4* dst, int bidx) {
        const float* bb = bias + 4 * (bidx * BQ);
        const float* wb = W + 4 * (bidx * BQ);
        #pragma unroll
        for (int j = 0; j < BQ; ++j) {
            dst[j * V + 0] = *(const float4*)(bb + 4 * j);
            #pragma unroll
            for (int k = 0; k < K; ++k)
                dst[j * V + 1 + k] = *(const float4*)(wb + k * DD + 4 * j);
        }
    };

    auto COMPUTE = [&](const float4* src, int bidx) {
        QP pb; v2f tt;
        #pragma unroll
        for (int j = 0; j < BQ; ++j) {
            const float4 b4 = src[j * V + 0];
            v2f l0 = vsplat(b4.x), l1 = vsplat(b4.y), l2 = vsplat(b4.z), l3 = vsplat(b4.w);
            #pragma unroll
            for (int k = 0; k < K; ++k) {
                const float4 w4 = src[j * V + 1 + k];
                l0 = VFMA(xv[k], vsplat(w4.x), l0);
                l1 = VFMA(xv[k], vsplat(w4.y), l1);
                l2 = VFMA(xv[k], vsplat(w4.z), l2);
                l3 = VFMA(xv[k], vsplat(w4.w), l3);
            }
            const v2f n2 = VFMA(l0, l0, VFMA(l1, l1, VFMA(l2, l2, l3 * l3)));
            rrA += __builtin_amdgcn_rsqf(n2.x);
            rrB += __builtin_amdgcn_rsqf(n2.y);
            QP q; q.w = l0; q.x = l1; q.y = l2; q.z = l3;
            if (j == 0) { pb = q; tt = n2; }
            else        { pb = qmulp(pb, q); tt *= n2; }
        }
        // exact power-of-2 rescale: m = tt*2^(-2*e2) in [1,4); M *= m
        const int e2A = ((__float_as_int(tt.x) >> 23) - 127) >> 1;
        const int e2B = ((__float_as_int(tt.y) >> 23) - 127) >> 1;
        const float scA = __int_as_float((127 - e2A) << 23);
        const float scB = __int_as_float((127 - e2B) << 23);
        MA *= tt.x * (scA * scA);
        MB *= tt.y * (scB * scB);
        v2f sc; sc.x = scA; sc.y = scB;
        pb.w *= sc; pb.x *= sc; pb.y *= sc; pb.z *= sc;
        if (bidx == 0) p = pb;
        else           p = qmulp(p, pb);
    };

    LOADB(A, 0);
    for (int gg = 0; gg < NB / 2; ++gg) {
        LOADB(Bb, 2 * gg + 1);
        COMPUTE(A, 2 * gg);
        const int nb = (2 * gg + 2 < NB) ? (2 * gg + 2) : (NB - 1);
        LOADB(A, nb);
        COMPUTE(Bb, 2 * gg + 1);
    }

    // per-row final normalize: / (sqrt(M) * (1 + eps*sum(1/n)))
    {
        const float invA = 1.0f / (sqrtf(MA) * fmaf(1e-8f, rrA, 1.0f));
        const float invB = 1.0f / (sqrtf(MB) * fmaf(1e-8f, rrB, 1.0f));
        v2f iv; iv.x = invA; iv.y = invB;
        p.w *= iv; p.x *= iv; p.y *= iv; p.z *= iv;
    }

    const int lane = t & 63;
    p = wave_ordered_prod_p(p, lane);

    const int w = t >> 6;             // 0..1
    if (lane == 0) {
        float* s8 = sprod + w * 8;
        s8[0] = p.w.x; s8[1] = p.x.x; s8[2] = p.y.x; s8[3] = p.z.x;   // A-half
        s8[4] = p.w.y; s8[5] = p.x.y; s8[6] = p.y.y; s8[7] = p.z.y;   // B-half
    }
    __syncthreads();
    if (t == 0) {
        // order: rows 0..63 (w0 A), 64..127 (w1 A), 128..191 (w0 B), 192..255 (w1 B)
        QF A0 = { sprod[0], sprod[1], sprod[2], sprod[3] };
        QF A1 = { sprod[8], sprod[9], sprod[10], sprod[11] };
        QF B0 = { sprod[4], sprod[5], sprod[6], sprod[7] };
        QF B1 = { sprod[12], sprod[13], sprod[14], sprod[15] };
        QF r = qmulf(qmulf(qmulf(A0, A1), B0), B1);
        float4 outv = { r.w, r.x, r.y, r.z };
        *(float4*)out4 = outv;
    }
}

__global__ __launch_bounds__(128) void worker_kernel(
    const float* __restrict__ vis, const float* __restrict__ txt, const float* __restrict__ gen,
    const float* __restrict__ Wv, const float* __restrict__ bv,
    const float* __restrict__ Wt, const float* __restrict__ bt,
    const float* __restrict__ Wg, const float* __restrict__ bg,
    float* __restrict__ wsf, double* __restrict__ dws)
{
    __shared__ double sred[128];
    float* sprod = (float*)sred;

    const int t  = threadIdx.x;
    const int id = blockIdx.x;

    if (id < 128) {
        const int b = id >> 4, chunk = id & 15;
        chain_pair<3, 4>(vis + (size_t)b * HW * 3, Wv, bv, chunk * 256,
                         wsf + (size_t)id * 4, sprod);
    } else if (id < 384) {
        const int i2 = id - 128;
        const int b = i2 >> 5, chunk = i2 & 31;
        chain_pair<1, 4>(txt + (size_t)b * LTXT, Wt, bt, chunk * 256,
                         wsf + 512 + (size_t)i2 * 4, sprod);
    } else if (id < 512) {
        const int i2 = id - 384;
        const int b = i2 >> 4, chunk = i2 & 15;
        chain_pair<4, 2>(gen + (size_t)b * GG * 4, Wg, bg, chunk * 256,
                         wsf + 1536 + (size_t)i2 * 4, sprod);
    } else if (id < 544) {
        // ---------------- vision audit: thread = row ----------------
        const int aid = id - 512;
        const int r = aid * 128 + t;          // 0..4095
        float gx[8], gy[8], gz[8];
        {
            float vx[8], vy[8], vz[8];
            #pragma unroll
            for (int b = 0; b < 8; ++b) {
                const size_t base = ((size_t)b * HW + r) * 3;
                vx[b] = vis[base]; vy[b] = vis[base+1]; vz[b] = vis[base+2];
            }
            #pragma unroll
            for (int b = 0; b < 8; ++b) {
                if (b == 0)      { gx[b] = vx[1]-vx[0];  gy[b] = vy[1]-vy[0];  gz[b] = vz[1]-vz[0]; }
                else if (b == 7) { gx[b] = vx[7]-vx[6];  gy[b] = vy[7]-vy[6];  gz[b] = vz[7]-vz[6]; }
                else             { gx[b] = (vx[b+1]-vx[b-1])*0.5f; gy[b] = (vy[b+1]-vy[b-1])*0.5f; gz[b] = (vz[b+1]-vz[b-1])*0.5f; }
            }
        }
        double acc = 0.0;
        #pragma unroll 4
        for (int i = 0; i < 64; ++i) {
            const float4 a0 = *(const float4*)(Wv + 4*i);
            const float4 a1 = *(const float4*)(Wv + DD + 4*i);
            const float4 a2 = *(const float4*)(Wv + 2*DD + 4*i);
            const float wq0 = a0.x + a0.y + a0.z + a0.w;
            const float wq1 = a1.x + a1.y + a1.z + a1.w;
            const float wq2 = a2.x + a2.y + a2.z + a2.w;
            float acc8 = 0.0f;
            #pragma unroll
            for (int b = 0; b < 8; ++b)
                acc8 += fabsf(fmaf(gx[b], wq0, fmaf(gy[b], wq1, gz[b] * wq2)));
            acc += (double)acc8;
        }
        sred[t] = acc;
        __syncthreads();
        for (int off = 64; off > 0; off >>= 1) {
            if (t < off) sred[t] += sred[t + off];
            __syncthreads();
        }
        if (t == 0) dws[aid] = sred[0];
    } else {
        // ---------------- text audit (gradient factor) ----------------
        const int aid = id - 544;
        const int l = aid * 128 + t;          // 0..8191
        float tv[8];
        #pragma unroll
        for (int b = 0; b < 8; ++b) tv[b] = txt[(size_t)b * LTXT + l];
        double acc = 0.0;
        #pragma unroll
        for (int b = 0; b < 8; ++b) {
            float gb;
            if (b == 0)      gb = tv[1] - tv[0];
            else if (b == 7) gb = tv[7] - tv[6];
            else             gb = (tv[b+1] - tv[b-1]) * 0.5f;
            acc += (double)fabsf(gb);
        }
        sred[t] = acc;
        __syncthreads();
        for (int off = 64; off > 0; off >>= 1) {
            if (t < off) sred[t] += sred[t + off];
            __syncthreads();
        }
        if (t == 0) dws[32 + aid] = sred[0];
    }
}

__global__ __launch_bounds__(256) void finalize_kernel(
    const float* __restrict__ vis, const float* __restrict__ txt, const float* __restrict__ gen,
    const float* __restrict__ Wv, const float* __restrict__ bv,
    const float* __restrict__ Wt, const float* __restrict__ bt,
    const float* __restrict__ Wg, const float* __restrict__ bg,
    const float* __restrict__ wsf, const double* __restrict__ dws,
    float* __restrict__ out)
{
    __shared__ float sphi[24];      // phi[m][b]
    __shared__ double sred[256];
    __shared__ double s_sumv, s_sumt, s_sumw;
    const int t = threadIdx.x;
    const int lane = t & 63, w = t >> 6;

    // each wave handles 6 (m,b) pairs; lane-per-chunk ordered butterfly combine
    #pragma unroll
    for (int j = 0; j < 6; ++j) {
        const int pair = w * 6 + j;          // 0..23
        const int m = pair >> 3, b = pair & 7;
        const int nch = (m == 1) ? 32 : 16;
        const float* base = wsf + ((m == 0) ? 0 : (m == 1) ? 512 : 1536) + (size_t)b * nch * 4;
        QF p = { 1.0f, 0.0f, 0.0f, 0.0f };
        if (lane < nch) {
            const float4 c0 = *(const float4*)(base + lane * 4);
            p = { c0.x, c0.y, c0.z, c0.w };
        }
        p = wave_ordered_prod(p, lane);
        if (lane == 0) {
            float lat[4];
            if (m == 0) {
                const float x0 = vis[(size_t)b*HW*3], x1 = vis[(size_t)b*HW*3+1], x2 = vis[(size_t)b*HW*3+2];
                #pragma unroll
                for (int c = 0; c < 4; ++c)
                    lat[c] = fmaf(x0, Wv[c], fmaf(x1, Wv[DD+c], fmaf(x2, Wv[2*DD+c], bv[c])));
            } else if (m == 1) {
                const float x0 = txt[(size_t)b*LTXT];
                #pragma unroll
                for (int c = 0; c < 4; ++c) lat[c] = fmaf(x0, Wt[c], bt[c]);
            } else {
                const float x0 = gen[(size_t)b*GG*4], x1 = gen[(size_t)b*GG*4+1],
                            x2 = gen[(size_t)b*GG*4+2], x3 = gen[(size_t)b*GG*4+3];
                #pragma unroll
                for (int c = 0; c < 4; ++c)
                    lat[c] = fmaf(x0, Wg[c], fmaf(x1, Wg[DD+c], fmaf(x2, Wg[2*DD+c], fmaf(x3, Wg[3*DD+c], bg[c]))));
            }
            const float n = sqrtf(fmaf(lat[0], lat[0], fmaf(lat[1], lat[1], fmaf(lat[2], lat[2], lat[3] * lat[3]))));
            const float inv = 1.0f / (n + 1e-8f);
            QF q0 = { lat[0]*inv, lat[1]*inv, lat[2]*inv, lat[3]*inv };
            p = qmulf(p, q0);
            float ww = p.w;
            ww = fminf(1.0f, fmaxf(-1.0f, ww));
            sphi[pair] = 2.0f * acosf(ww);
        }
    }
    __syncthreads();

    // vision audit sum (32 partials)
    sred[t] = (t < 32) ? dws[t] : 0.0; __syncthreads();
    for (int off = 128; off > 0; off >>= 1) { if (t < off) sred[t] += sred[t+off]; __syncthreads(); }
    if (t == 0) s_sumv = sred[0];
    __syncthreads();

    // text audit sum (64 partials)
    sred[t] = (t < 64) ? dws[32 + t] : 0.0; __syncthreads();
    for (int off = 128; off > 0; off >>= 1) { if (t < off) sred[t] += sred[t+off]; __syncthreads(); }
    if (t == 0) s_sumt = sred[0];
    __syncthreads();

    // sum_i |wtq_i|
    double aw = 0.0;
    if (t < 64) {
        const int d0 = 4 * t;
        aw = (double)fabsf(Wt[d0] + Wt[d0+1] + Wt[d0+2] + Wt[d0+3]);
    }
    sred[t] = aw; __syncthreads();
    for (int off = 128; off > 0; off >>= 1) { if (t < off) sred[t] += sred[t+off]; __syncthreads(); }
    if (t == 0) s_sumw = sred[0];
    __syncthreads();

    if (t == 0) {
        float mv = 0.0f, mt = 0.0f;
        for (int b = 0; b < 8; ++b) { mv += sphi[b]; mt += sphi[8 + b]; }
        mv *= 0.125f; mt *= 0.125f;
        const float interf = fabsf(mv - mt);
        for (int b = 0; b < 8; ++b)
            out[b] = expf(-fabsf(sphi[16 + b] - interf));
        out[8]  = interf;
        out[9]  = (float)(s_sumv / 2097152.0);            // 8 * 4096 * 64
        out[10] = (float)(s_sumt * s_sumw / 4194304.0);   // 8 * 8192 * 64
    }
}

extern "C" void kernel_launch(void* const* d_in, const int* in_sizes, int n_in,
                              void* d_out, int out_size, void* d_ws, size_t ws_size,
                              hipStream_t stream) {
    (void)in_sizes; (void)n_in; (void)out_size; (void)ws_size;
    const float* vis = (const float*)d_in[0];
    const float* txt = (const float*)d_in[1];
    const float* gen = (const float*)d_in[2];
    const float* Wv  = (const float*)d_in[3];
    const float* bv  = (const float*)d_in[4];
    const float* Wt  = (const float*)d_in[5];
    const float* bt  = (const float*)d_in[6];
    const float* Wg  = (const float*)d_in[7];
    const float* bg  = (const float*)d_in[8];
    float*  wsf = (float*)d_ws;
    double* dws = (double*)((char*)d_ws + 65536);
    float*  out = (float*)d_out;

    hipLaunchKernelGGL(worker_kernel, dim3(608), dim3(128), 0, stream,
                       vis, txt, gen, Wv, bv, Wt, bt, Wg, bg, wsf, dws);
    hipLaunchKernelGGL(finalize_kernel, dim3(1), dim3(256), 0, stream,
                       vis, txt, gen, Wv, bv, Wt, bt, Wg, bg, wsf, dws, out);
}